// Round 4
// baseline (2325.252 us; speedup 1.0000x reference)
//
#include <hip/hip_runtime.h>
#include <cstdint>

#define NNODES 10000
#define FDIM 128
#define FEAT_ELEMS (NNODES * FDIM)

// Module-owned scratch for the aggregation buffer (5.12 MB BSS).
// Referenced directly from kernels — no host-side symbol lookup needed.
__device__ float g_agg[FEAT_ELEMS];

// -------- zero g_agg (float4 grid-stride) ---------------------------------
__global__ __launch_bounds__(256) void zero_agg_kernel() {
  int i = blockIdx.x * blockDim.x + threadIdx.x;
  if (i < FEAT_ELEMS / 4) ((float4*)g_agg)[i] = make_float4(0.f, 0.f, 0.f, 0.f);
}

// -------- scatter-add: g_agg[dst] += feat[src], edge-parallel -------------
// 32 threads per edge, float4 per thread (4 atomicAdds).
// edge_index arrives as int32 (harness converts integer inputs to int).
__global__ __launch_bounds__(256) void scatter_add_kernel(
    const float* __restrict__ feat,
    const int* __restrict__ ei,        // [2, E] as int32
    int E_) {
  int gid = blockIdx.x * blockDim.x + threadIdx.x;   // E*32 = 20.48M < 2^31
  if (gid >= E_ * 32) return;
  int e = gid >> 5;
  int f = (gid & 31) << 2;
  int s = ei[e];         // src
  int d = ei[E_ + e];    // dst
  float4 v = *(const float4*)(feat + (size_t)s * FDIM + f);
  float* o = g_agg + (size_t)d * FDIM + f;
  atomicAdd(o + 0, v.x);
  atomicAdd(o + 1, v.y);
  atomicAdd(o + 2, v.z);
  atomicAdd(o + 3, v.w);
}

// -------- fused (xin + g_agg) @ w + b, epilogue relu / log_softmax --------
// w is [K=128, F=128] (k-major: out[f] = sum_k in[k]*w[k*128+f]). Staged in
// LDS (64 KB). One row per wave: lane owns output features (lane, lane+64);
// row values held 2/lane in registers, broadcast via __shfl.
// MODE 0: relu. MODE 1: log_softmax.
// out may alias xin (in-place): each wave reads its row into registers
// before writing it, and no other wave touches that row.
template <int MODE>
__global__ __launch_bounds__(256) void gemm_fused_kernel(
    const float* xin,
    const float* __restrict__ w,
    const float* __restrict__ b,
    float* out) {
  __shared__ float wl[FDIM * FDIM];     // exactly 64 KB
  const int tid = threadIdx.x;

  for (int i = tid * 4; i < FDIM * FDIM; i += 1024)
    *(float4*)(wl + i) = *(const float4*)(w + i);
  __syncthreads();

  const int wave = tid >> 6, lane = tid & 63;
  const float b0 = b[lane], b1 = b[lane + 64];
  const int row0 = blockIdx.x * 32;

  for (int r = wave; r < 32; r += 4) {            // 8 rows per wave
    const int row = row0 + r;
    if (row >= NNODES) break;
    const float* xr = xin   + (size_t)row * FDIM;
    const float* ar = g_agg + (size_t)row * FDIM;
    const float r0 = xr[lane]      + ar[lane];
    const float r1 = xr[lane + 64] + ar[lane + 64];

    float acc0 = b0, acc1 = b1;
#pragma unroll 8
    for (int k = 0; k < FDIM; k++) {
      const float v = __shfl((k < 64) ? r0 : r1, k & 63, 64); // uniform sel
      acc0 = fmaf(v, wl[k * FDIM + lane],      acc0);  // 2-way bank alias: free
      acc1 = fmaf(v, wl[k * FDIM + lane + 64], acc1);
    }

    float* orow = out + (size_t)row * FDIM;
    if (MODE == 0) {
      orow[lane]      = fmaxf(acc0, 0.f);
      orow[lane + 64] = fmaxf(acc1, 0.f);
    } else {
      // log_softmax over the 128 values held by this wave (2 per lane)
      float m = fmaxf(acc0, acc1);
#pragma unroll
      for (int off = 32; off >= 1; off >>= 1)
        m = fmaxf(m, __shfl_xor(m, off, 64));
      float s2 = __expf(acc0 - m) + __expf(acc1 - m);
#pragma unroll
      for (int off = 32; off >= 1; off >>= 1)
        s2 += __shfl_xor(s2, off, 64);
      const float ls = m + __logf(s2);            // logsumexp
      orow[lane]      = acc0 - ls;
      orow[lane + 64] = acc1 - ls;
    }
  }
}

extern "C" void kernel_launch(void* const* d_in, const int* in_sizes, int n_in,
                              void* d_out, int out_size, void* d_ws, size_t ws_size,
                              hipStream_t stream) {
  const float* x  = (const float*)d_in[0];
  const int*   ei = (const int*)d_in[1];     // int64 in reference -> int32 here
  const float* w1 = (const float*)d_in[2];
  const float* b1 = (const float*)d_in[3];
  const float* w2 = (const float*)d_in[4];
  const float* b2 = (const float*)d_in[5];
  float* out = (float*)d_out;

  const int E_ = in_sizes[1] / 2;

  const int zblocks = (FEAT_ELEMS / 4 + 255) / 256;
  const int sblocks = (E_ * 32 + 255) / 256;
  const int gblocks = (NNODES + 31) / 32;

  // ---- layer 1 ----  (h1 stored in d_out)
  zero_agg_kernel<<<zblocks, 256, 0, stream>>>();
  scatter_add_kernel<<<sblocks, 256, 0, stream>>>(x, ei, E_);
  gemm_fused_kernel<0><<<gblocks, 256, 0, stream>>>(x, w1, b1, out);

  // ---- layer 2 ----  (in-place on d_out)
  zero_agg_kernel<<<zblocks, 256, 0, stream>>>();
  scatter_add_kernel<<<sblocks, 256, 0, stream>>>(out, ei, E_);
  gemm_fused_kernel<1><<<gblocks, 256, 0, stream>>>(out, w2, b2, out);
}

// Round 5
// 281.321 us; speedup vs baseline: 8.2655x; 8.2655x over previous
//
#include <hip/hip_runtime.h>
#include <cstdint>

#define NNODES 10000
#define FDIM 128
#define MAXEDGES 640000

// Module-owned scratch (BSS) — no d_ws / symbol-address API dependence.
__device__ int   g_deg[NNODES];
__device__ int   g_rowptr[NNODES + 1];
__device__ int   g_pos[NNODES];
__device__ int   g_csr_src[MAXEDGES];
__device__ float g_h1[NNODES * FDIM];

// ---------------- CSR build ----------------------------------------------
__global__ __launch_bounds__(256) void zero_deg_kernel() {
  int i = blockIdx.x * 256 + threadIdx.x;
  if (i < NNODES) g_deg[i] = 0;
}

__global__ __launch_bounds__(256) void hist_kernel(const int* __restrict__ ei, int E_) {
  int e = blockIdx.x * 256 + threadIdx.x;
  if (e < E_) atomicAdd(&g_deg[ei[E_ + e]], 1);
}

// single-block exclusive scan of g_deg -> g_rowptr (and g_pos copy)
__global__ __launch_bounds__(1024) void scan_kernel(int E_) {
  __shared__ int tot[1024];
  const int t = threadIdx.x;
  const int per = (NNODES + 1023) / 1024;   // 10
  int local[(NNODES + 1023) / 1024];
  int base = t * per;
  int sum = 0;
  for (int i = 0; i < per; i++) {
    int idx = base + i;
    int v = (idx < NNODES) ? g_deg[idx] : 0;
    local[i] = sum;                          // exclusive within chunk
    sum += v;
  }
  tot[t] = sum;
  __syncthreads();
  // Hillis-Steele inclusive scan over 1024 partials
  for (int off = 1; off < 1024; off <<= 1) {
    int v = (t >= off) ? tot[t - off] : 0;
    __syncthreads();
    tot[t] += v;
    __syncthreads();
  }
  int prev = (t == 0) ? 0 : tot[t - 1];
  for (int i = 0; i < per; i++) {
    int idx = base + i;
    if (idx < NNODES) {
      int r = prev + local[i];
      g_rowptr[idx] = r;
      g_pos[idx] = r;
    }
  }
  if (t == 0) g_rowptr[NNODES] = E_;
}

__global__ __launch_bounds__(256) void fill_kernel(const int* __restrict__ ei, int E_) {
  int e = blockIdx.x * 256 + threadIdx.x;
  if (e < E_) {
    int d = ei[E_ + e];
    int p = atomicAdd(&g_pos[d], 1);
    g_csr_src[p] = ei[e];
  }
}

// ---------------- fused GIN layer: gather-reduce + GEMM + epilogue --------
// One wave per node (grid-stride). Lane owns features (2*lane, 2*lane+1):
// gather loads are coalesced float2; W (k-major [128,128]) staged in 64 KB
// LDS, read as float2; row values broadcast to the k-loop via __shfl.
// MODE 0: xin = param, out = g_h1, epilogue ReLU.
// MODE 1: xin = g_h1, out = param, epilogue log_softmax.
template <int MODE>
__global__ __launch_bounds__(256) void gin_layer_kernel(
    const float* __restrict__ xin_g,
    const float* __restrict__ w,
    const float* __restrict__ b,
    float* __restrict__ out_g,
    int nwaves_total) {
  const float* xin = (MODE == 1) ? (const float*)g_h1 : xin_g;
  float* out = (MODE == 0) ? (float*)g_h1 : out_g;

  __shared__ float wl[FDIM * FDIM];       // exactly 64 KB
  const int tid = threadIdx.x;
  for (int i = tid * 4; i < FDIM * FDIM; i += 1024)
    *(float4*)(wl + i) = *(const float4*)(w + i);
  __syncthreads();

  const int wave = tid >> 6, lane = tid & 63;
  const int gw = blockIdx.x * 4 + wave;
  const float2 bb = *(const float2*)(b + 2 * lane);

  for (int row = gw; row < NNODES; row += nwaves_total) {
    // own row ((1+eps)*x with eps=0)
    float2 rv = *(const float2*)(xin + (size_t)row * FDIM + 2 * lane);
    float r0 = rv.x, r1 = rv.y;

    // gather-reduce over in-edges (no atomics)
    int p = g_rowptr[row];
    const int end = g_rowptr[row + 1];
    while (p < end) {
      int n = end - p; if (n > 64) n = 64;
      int myedge = (lane < n) ? g_csr_src[p + lane] : 0;
      int j = 0;
      for (; j + 4 <= n; j += 4) {       // 4 independent loads in flight
        int s0 = __shfl(myedge, j,     64);
        int s1 = __shfl(myedge, j + 1, 64);
        int s2 = __shfl(myedge, j + 2, 64);
        int s3 = __shfl(myedge, j + 3, 64);
        float2 v0 = *(const float2*)(xin + (size_t)s0 * FDIM + 2 * lane);
        float2 v1 = *(const float2*)(xin + (size_t)s1 * FDIM + 2 * lane);
        float2 v2 = *(const float2*)(xin + (size_t)s2 * FDIM + 2 * lane);
        float2 v3 = *(const float2*)(xin + (size_t)s3 * FDIM + 2 * lane);
        r0 += (v0.x + v1.x) + (v2.x + v3.x);
        r1 += (v0.y + v1.y) + (v2.y + v3.y);
      }
      for (; j < n; j++) {
        int s0 = __shfl(myedge, j, 64);
        float2 v0 = *(const float2*)(xin + (size_t)s0 * FDIM + 2 * lane);
        r0 += v0.x; r1 += v0.y;
      }
      p += n;
    }

    // GEMM: out[f] = b[f] + sum_k h[k]*w[k*128+f], f in {2*lane, 2*lane+1}
    float acc0 = bb.x, acc1 = bb.y;
#pragma unroll 16
    for (int kk = 0; kk < 64; kk++) {
      float v0 = __shfl(r0, kk, 64);     // h[2*kk]
      float v1 = __shfl(r1, kk, 64);     // h[2*kk+1]
      float2 w0 = *(const float2*)(wl + (2 * kk)     * FDIM + 2 * lane);
      float2 w1 = *(const float2*)(wl + (2 * kk + 1) * FDIM + 2 * lane);
      acc0 = fmaf(v1, w1.x, fmaf(v0, w0.x, acc0));
      acc1 = fmaf(v1, w1.y, fmaf(v0, w0.y, acc1));
    }

    float* orow = out + (size_t)row * FDIM + 2 * lane;
    if (MODE == 0) {
      *(float2*)orow = make_float2(fmaxf(acc0, 0.f), fmaxf(acc1, 0.f));
    } else {
      float m = fmaxf(acc0, acc1);
#pragma unroll
      for (int off = 32; off >= 1; off >>= 1)
        m = fmaxf(m, __shfl_xor(m, off, 64));
      float s2 = __expf(acc0 - m) + __expf(acc1 - m);
#pragma unroll
      for (int off = 32; off >= 1; off >>= 1)
        s2 += __shfl_xor(s2, off, 64);
      const float ls = m + __logf(s2);
      *(float2*)orow = make_float2(acc0 - ls, acc1 - ls);
    }
  }
}

extern "C" void kernel_launch(void* const* d_in, const int* in_sizes, int n_in,
                              void* d_out, int out_size, void* d_ws, size_t ws_size,
                              hipStream_t stream) {
  const float* x  = (const float*)d_in[0];
  const int*   ei = (const int*)d_in[1];     // int64 in reference -> int32 here
  const float* w1 = (const float*)d_in[2];
  const float* b1 = (const float*)d_in[3];
  const float* w2 = (const float*)d_in[4];
  const float* b2 = (const float*)d_in[5];
  float* out = (float*)d_out;

  const int E_ = in_sizes[1] / 2;

  const int nblocks = (NNODES + 255) / 256;
  const int eblocks = (E_ + 255) / 256;

  // ---- CSR build (once per call, reused by both layers) ----
  zero_deg_kernel<<<nblocks, 256, 0, stream>>>();
  hist_kernel<<<eblocks, 256, 0, stream>>>(ei, E_);
  scan_kernel<<<1, 1024, 0, stream>>>(E_);
  fill_kernel<<<eblocks, 256, 0, stream>>>(ei, E_);

  // ---- fused layers ----
  // 512 blocks = 2 blocks/CU (LDS-limited), 2048 waves; each wave ~5 nodes.
  const int LBLOCKS = 512, NW = LBLOCKS * 4;
  gin_layer_kernel<0><<<LBLOCKS, 256, 0, stream>>>(x, w1, b1, nullptr, NW);
  gin_layer_kernel<1><<<LBLOCKS, 256, 0, stream>>>(nullptr, w2, b2, out, NW);
}